// Round 5
// baseline (490.776 us; speedup 1.0000x reference)
//
#include <hip/hip_runtime.h>
#include <hip/hip_bf16.h>

// Problem constants (from reference)
#define U_CNT   100000
#define I_CNT   50000
#define D_DIM   64
#define N_NODES 150000   // U+I
#define NNZ_E   3200000
#define B_SZ    4096

#define TILE1_E 4096     // scatter pass: edges per block (16 per thread)
#define N_TILES1 ((NNZ_E + TILE1_E - 1) / TILE1_E)

// Per-row fixed-capacity window in meta. deg ~ Poisson(21.3); E[max over
// 150K rows] ~ 44; P(any row > 56) ~ 3e-5. Overflow guarded (edge dropped).
// 56*8B = 448B/row (64B-aligned since 448 = 7 lines).
#define CAP_ROW 56

// convert work fused into scatter as extra blocks
#define CONV_THREADS (N_NODES * 16)
#define CONV_BLOCKS ((CONV_THREADS + 255) / 256)

typedef unsigned int uint;
typedef unsigned short ushort_t;
typedef _Float16 half_t;
typedef half_t half2_t __attribute__((ext_vector_type(2)));

union h2u_t { uint u; half2_t h; };
__device__ __forceinline__ half2_t u2h2(uint u) { h2u_t c; c.u = u; return c.h; }
__device__ __forceinline__ uint h22u(half2_t h) { h2u_t c; c.h = h; return c.u; }
__device__ __forceinline__ half2_t h2shfl_xor(half2_t v, int m) {
    h2u_t c; c.h = v; c.u = (uint)__shfl_xor((int)c.u, m, 64); return c.h;
}
__device__ __forceinline__ float h2lo(uint u) { return (float)u2h2(u)[0]; }
__device__ __forceinline__ float h2hi(uint u) { return (float)u2h2(u)[1]; }

// ---------------- row cursor init ----------------
__global__ __launch_bounds__(256) void init_rowcur_kernel(int* __restrict__ rowcur) {
    int i = blockIdx.x * 256 + threadIdx.x;
    if (i < N_NODES) rowcur[i] = i * CAP_ROW;
}

// ---------------- Direct scatter (replaces super+sub+row_sort) ----------------
// Each edge: atomicAdd on its row's cursor -> write final-format CSR entry
// (col, half2(val,val)) into the row's fixed 56-slot window. Counters are
// 0.6MB (L2-resident), avg 21 ops/counter over the whole kernel -> no
// hot-spot. Blocks >= N_TILES1 do the independent ego->fp16 convert.
__global__ __launch_bounds__(256) void scatter_kernel(const int* __restrict__ rows,
                                                      const int* __restrict__ cols,
                                                      const float* __restrict__ vals,
                                                      int* __restrict__ rowcur,
                                                      int2* __restrict__ meta,
                                                      const float4* __restrict__ ue4,
                                                      const float4* __restrict__ ie4,
                                                      uint2* __restrict__ e2) {
    int tid = threadIdx.x;

    if (blockIdx.x >= N_TILES1) {
        // fused convert: ego -> fp16
        int g = (blockIdx.x - N_TILES1) * 256 + tid;
        if (g < CONV_THREADS) {
            float4 f = (g < U_CNT * 16) ? ue4[g] : ie4[g - U_CNT * 16];
            half2_t a = { (half_t)f.x, (half_t)f.y };
            half2_t b = { (half_t)f.z, (half_t)f.w };
            uint2 o; o.x = h22u(a); o.y = h22u(b);
            e2[g] = o;
        }
        return;
    }

    int base = blockIdx.x * TILE1_E;
    int nk = NNZ_E - base - tid;
    nk = (nk <= 0) ? 0 : (nk + 255) >> 8;

    // phase A: coalesced edge loads (16 independent)
    int rr[16]; int cc[16]; float vv[16];
    #pragma unroll
    for (int k = 0; k < 16; ++k) {
        if (k < nk) {
            int j = base + tid + (k << 8);
            rr[k] = rows[j];
            cc[k] = cols[j];
            vv[k] = vals[j];
        }
    }
    // phase B: 16 independent atomic position claims (pipelined L2 round trips)
    int pos[16];
    #pragma unroll
    for (int k = 0; k < 16; ++k) {
        if (k < nk) pos[k] = atomicAdd(&rowcur[rr[k]], 1);
    }
    // phase C: scattered final-format writes
    #pragma unroll
    for (int k = 0; k < 16; ++k) {
        if (k < nk) {
            if (pos[k] < rr[k] * CAP_ROW + CAP_ROW) {
                half2_t hv = { (half_t)vv[k], (half_t)vv[k] };
                meta[pos[k]] = make_int2(cc[k], (int)h22u(hv));
            }
        }
    }
}

// ---------------- SpMM (gather-only, fp16 features, pk_fma) ----------------
// Wave: 8 edge-slots x 8 lanes; lane loads 16B (8 fp16) of the 128B row.
// 4-deep edge pipeline; row range implicit: [wid*CAP_ROW, rowcur[wid]).
// Phantom slots clamp to THIS ROW's last edge (fresh this run) with val=0.
__global__ __launch_bounds__(256) void spmm_fp16_kernel(const int* __restrict__ rowcur,
                                                        const int2* __restrict__ csr,
                                                        const ushort_t* __restrict__ x,
                                                        ushort_t* __restrict__ out) {
    int wid  = (blockIdx.x * blockDim.x + threadIdx.x) >> 6;
    int lane = threadIdx.x & 63;
    int sub  = lane >> 3;   // edge slot 0..7
    int l8   = lane & 7;    // 16B chunk within row
    if (wid >= N_NODES) return;
    int s = wid * CAP_ROW;
    int e = rowcur[wid];
    int cap = s + CAP_ROW; if (e > cap) e = cap;
    const uint4* x4 = (const uint4*)x;

    half2_t a0 = { (half_t)0, (half_t)0 };
    half2_t a1 = a0, a2 = a0, a3 = a0;

    if (e > s) {
        int last = e - 1;   // fresh edge (valid col); clamp target for phantoms
        auto ld = [&](int jj) -> int2 {
            int2 c = csr[jj < e ? jj : last];
            if (jj >= e) c.y = 0;   // phantom: exact-zero contribution
            return c;
        };
        int j = s + sub;
        int2 c0 = ld(j);
        int2 c1 = ld(j + 8);
        int2 c2 = ld(j + 16);
        int2 c3 = ld(j + 24);
        for (; j < e; j += 32) {
            uint4 x0 = x4[(size_t)c0.x * 8 + l8];
            uint4 x1 = x4[(size_t)c1.x * 8 + l8];
            uint4 x2 = x4[(size_t)c2.x * 8 + l8];
            uint4 x3 = x4[(size_t)c3.x * 8 + l8];
            int jn = j + 32;
            int2 n0 = ld(jn);
            int2 n1 = ld(jn + 8);
            int2 n2 = ld(jn + 16);
            int2 n3 = ld(jn + 24);
            half2_t v0 = u2h2((uint)c0.y);
            a0 += u2h2(x0.x) * v0; a1 += u2h2(x0.y) * v0;
            a2 += u2h2(x0.z) * v0; a3 += u2h2(x0.w) * v0;
            half2_t v1 = u2h2((uint)c1.y);
            a0 += u2h2(x1.x) * v1; a1 += u2h2(x1.y) * v1;
            a2 += u2h2(x1.z) * v1; a3 += u2h2(x1.w) * v1;
            half2_t v2 = u2h2((uint)c2.y);
            a0 += u2h2(x2.x) * v2; a1 += u2h2(x2.y) * v2;
            a2 += u2h2(x2.z) * v2; a3 += u2h2(x2.w) * v2;
            half2_t v3 = u2h2((uint)c3.y);
            a0 += u2h2(x3.x) * v3; a1 += u2h2(x3.y) * v3;
            a2 += u2h2(x3.z) * v3; a3 += u2h2(x3.w) * v3;
            c0 = n0; c1 = n1; c2 = n2; c3 = n3;
        }
    }
    a0 += h2shfl_xor(a0, 8);  a1 += h2shfl_xor(a1, 8);
    a2 += h2shfl_xor(a2, 8);  a3 += h2shfl_xor(a3, 8);
    a0 += h2shfl_xor(a0, 16); a1 += h2shfl_xor(a1, 16);
    a2 += h2shfl_xor(a2, 16); a3 += h2shfl_xor(a3, 16);
    a0 += h2shfl_xor(a0, 32); a1 += h2shfl_xor(a1, 32);
    a2 += h2shfl_xor(a2, 32); a3 += h2shfl_xor(a3, 32);

    if (sub == 0) {
        uint4 r;
        r.x = h22u(a0); r.y = h22u(a1); r.z = h22u(a2); r.w = h22u(a3);
        ((uint4*)out)[(size_t)wid * 8 + l8] = r;
    }
}

// ---------------- Epilogue ----------------
__global__ __launch_bounds__(256) void epilogue_kernel(const int* __restrict__ users,
                                                       const int* __restrict__ items,
                                                       const int* __restrict__ rowcur,
                                                       const int2* __restrict__ csr,
                                                       const ushort_t* __restrict__ ebuf,
                                                       const ushort_t* __restrict__ buf1,
                                                       const ushort_t* __restrict__ buf2,
                                                       const float* __restrict__ u_his,
                                                       const float* __restrict__ i_his,
                                                       const float* __restrict__ W,
                                                       const float* __restrict__ bvec,
                                                       float* __restrict__ out) {
    __shared__ float Wt[D_DIM * 65];
    __shared__ float bsh[D_DIM];
    __shared__ float on_s[4][D_DIM];
    for (int t = threadIdx.x; t < D_DIM * D_DIM; t += blockDim.x) {
        int j = t >> 6, k = t & 63;
        Wt[k * 65 + j] = W[t];
    }
    if (threadIdx.x < D_DIM) bsh[threadIdx.x] = bvec[threadIdx.x];

    int wv   = threadIdx.x >> 6;
    int wid  = blockIdx.x * 4 + wv;
    int lane = threadIdx.x & 63;
    int sub  = lane >> 4;   // 4 edge slots
    int l16  = lane & 15;   // 8B chunk (4 fp16) within 128B row

    bool is_user = (wid < B_SZ);
    int  samp = is_user ? wid : wid - B_SZ;
    int  idx  = is_user ? users[samp] : items[samp];
    int  row  = is_user ? idx : (U_CNT + idx);

    // hoist latency-long independent loads above the gather chain
    const float* his = is_user ? u_his : i_his;
    float hisv = his[(size_t)idx * D_DIM + lane];
    uint2 eg = make_uint2(0, 0), b1v = eg, b2v = eg;
    if (sub == 0) {
        eg  = ((const uint2*)ebuf)[(size_t)row * 16 + l16];
        b1v = ((const uint2*)buf1)[(size_t)row * 16 + l16];
        b2v = ((const uint2*)buf2)[(size_t)row * 16 + l16];
    }

    // layer-3 gather from buf2 (fp16, pk_fma), 4-deep edge pipeline, clamped
    int s = row * CAP_ROW;
    int e = rowcur[row];
    int cap = s + CAP_ROW; if (e > cap) e = cap;
    half2_t c0 = { (half_t)0, (half_t)0 };
    half2_t c1 = c0;
    if (e > s) {
        int last = e - 1;
        auto ld = [&](int jj) -> int2 {
            int2 c = csr[jj < e ? jj : last];
            if (jj >= e) c.y = 0;
            return c;
        };
        int j = s + sub;
        int2 e0 = ld(j);
        int2 e1 = ld(j + 4);
        int2 e2 = ld(j + 8);
        int2 e3 = ld(j + 12);
        for (; j < e; j += 16) {
            uint2 x0 = ((const uint2*)buf2)[(size_t)e0.x * 16 + l16];
            uint2 x1 = ((const uint2*)buf2)[(size_t)e1.x * 16 + l16];
            uint2 x2 = ((const uint2*)buf2)[(size_t)e2.x * 16 + l16];
            uint2 x3 = ((const uint2*)buf2)[(size_t)e3.x * 16 + l16];
            int jn = j + 16;
            int2 n0 = ld(jn);
            int2 n1 = ld(jn + 4);
            int2 n2 = ld(jn + 8);
            int2 n3 = ld(jn + 12);
            half2_t v0 = u2h2((uint)e0.y);
            c0 += u2h2(x0.x) * v0; c1 += u2h2(x0.y) * v0;
            half2_t v1 = u2h2((uint)e1.y);
            c0 += u2h2(x1.x) * v1; c1 += u2h2(x1.y) * v1;
            half2_t v2 = u2h2((uint)e2.y);
            c0 += u2h2(x2.x) * v2; c1 += u2h2(x2.y) * v2;
            half2_t v3 = u2h2((uint)e3.y);
            c0 += u2h2(x3.x) * v3; c1 += u2h2(x3.y) * v3;
            e0 = n0; e1 = n1; e2 = n2; e3 = n3;
        }
    }
    c0 += h2shfl_xor(c0, 16); c1 += h2shfl_xor(c1, 16);
    c0 += h2shfl_xor(c0, 32); c1 += h2shfl_xor(c1, 32);

    if (sub == 0) {
        on_s[wv][l16 * 4 + 0] = (h2lo(eg.x) + h2lo(b1v.x) + h2lo(b2v.x) + (float)c0[0]) * 0.25f;
        on_s[wv][l16 * 4 + 1] = (h2hi(eg.x) + h2hi(b1v.x) + h2hi(b2v.x) + (float)c0[1]) * 0.25f;
        on_s[wv][l16 * 4 + 2] = (h2lo(eg.y) + h2lo(b1v.y) + h2lo(b2v.y) + (float)c1[0]) * 0.25f;
        on_s[wv][l16 * 4 + 3] = (h2hi(eg.y) + h2hi(b1v.y) + h2hi(b2v.y) + (float)c1[1]) * 0.25f;
    }
    __syncthreads();

    float online = on_s[wv][lane];
    float target = 0.05f * hisv + 0.95f * online;

    float p = bsh[lane];
    #pragma unroll
    for (int k = 0; k < D_DIM; ++k) {
        float ok = __shfl(online, k, 64);
        p = fmaf(ok, Wt[k * 65 + lane], p);
    }

    size_t base = is_user ? 0 : (size_t)2 * B_SZ * D_DIM;
    out[base + (size_t)samp * D_DIM + lane] = p;
    out[base + (size_t)B_SZ * D_DIM + (size_t)samp * D_DIM + lane] = target;
}

// ---------------- launch ----------------

extern "C" void kernel_launch(void* const* d_in, const int* in_sizes, int n_in,
                              void* d_out, int out_size, void* d_ws, size_t ws_size,
                              hipStream_t stream) {
    const float* user_emb = (const float*)d_in[0];
    const float* item_emb = (const float*)d_in[1];
    const float* W        = (const float*)d_in[2];
    const float* bvec     = (const float*)d_in[3];
    const int*   adj_rows = (const int*)d_in[4];
    const int*   adj_cols = (const int*)d_in[5];
    const float* adj_vals = (const float*)d_in[6];
    const int*   users    = (const int*)d_in[7];
    const int*   items    = (const int*)d_in[8];
    const float* u_his    = (const float*)d_in[9];
    const float* i_his    = (const float*)d_in[10];
    float* out = (float*)d_out;

    char* ws = (char*)d_ws;
    size_t o = 0;
    ushort_t* ebuf  = (ushort_t*)(ws + o); o += (size_t)N_NODES * D_DIM * 2;       // 19.2MB
    ushort_t* buf1  = (ushort_t*)(ws + o); o += (size_t)N_NODES * D_DIM * 2;       // 19.2MB
    ushort_t* buf2  = (ushort_t*)(ws + o); o += (size_t)N_NODES * D_DIM * 2;       // 19.2MB
    int2*  meta     = (int2*)(ws + o);     o += (size_t)N_NODES * CAP_ROW * 8;     // 67.2MB
    int*   rowcur   = (int*)(ws + o);      o += (size_t)N_NODES * 4;               // 0.6MB
    (void)ws_size; (void)o; (void)in_sizes; (void)n_in; (void)out_size;

    // row cursors -> direct per-row scatter (replaces super+sub+row_sort).
    // convert (ego -> fp16) rides on the scatter grid as extra blocks.
    init_rowcur_kernel<<<(N_NODES + 255) / 256, 256, 0, stream>>>(rowcur);
    scatter_kernel<<<N_TILES1 + CONV_BLOCKS, 256, 0, stream>>>(
        adj_rows, adj_cols, adj_vals, rowcur, meta,
        (const float4*)user_emb, (const float4*)item_emb, (uint2*)ebuf);

    // layers 1 and 2 (full, fp16); layer 3 fused into epilogue
    int spmm_blocks = (N_NODES + 3) / 4;
    spmm_fp16_kernel<<<spmm_blocks, 256, 0, stream>>>(rowcur, meta, ebuf, buf1);
    spmm_fp16_kernel<<<spmm_blocks, 256, 0, stream>>>(rowcur, meta, buf1, buf2);

    epilogue_kernel<<<(2 * B_SZ) / 4, 256, 0, stream>>>(users, items, rowcur, meta,
                                                        ebuf, buf1, buf2,
                                                        u_his, i_his, W, bvec, out);
}

// Round 6
// 334.958 us; speedup vs baseline: 1.4652x; 1.4652x over previous
//
#include <hip/hip_runtime.h>
#include <hip/hip_bf16.h>

// Problem constants (from reference)
#define U_CNT   100000
#define I_CNT   50000
#define D_DIM   64
#define N_NODES 150000   // U+I
#define NNZ_E   3200000
#define B_SZ    4096

// Single-level scatter: 128-row buckets
#define NSUB 1172        // ceil(150000/128)
#define CAP2 4096        // per-bucket capacity (mean 2731, sigma 52 -> 26 sigma)
#define TILE_E 8192      // edges per scatter block (512 thr x 16)
#define N_TILES ((NNZ_E + TILE_E - 1) / TILE_E)

// convert work fused into scatter as extra blocks (4 float4 per thread)
#define CONV_THREADS (N_NODES * 16)
#define CONV_PER_BLK (512 * 4)
#define CONV_BLOCKS ((CONV_THREADS + CONV_PER_BLK - 1) / CONV_PER_BLK)

typedef unsigned int uint;
typedef unsigned short ushort_t;
typedef _Float16 half_t;
typedef half_t half2_t __attribute__((ext_vector_type(2)));

union h2u_t { uint u; half2_t h; };
__device__ __forceinline__ half2_t u2h2(uint u) { h2u_t c; c.u = u; return c.h; }
__device__ __forceinline__ uint h22u(half2_t h) { h2u_t c; c.h = h; return c.u; }
__device__ __forceinline__ half2_t h2shfl_xor(half2_t v, int m) {
    h2u_t c; c.h = v; c.u = (uint)__shfl_xor((int)c.u, m, 64); return c.h;
}
__device__ __forceinline__ float h2lo(uint u) { return (float)u2h2(u)[0]; }
__device__ __forceinline__ float h2hi(uint u) { return (float)u2h2(u)[1]; }

// ---------------- cursor init ----------------
__global__ __launch_bounds__(256) void init_cursors_kernel(int* __restrict__ subcursor) {
    int i = blockIdx.x * 256 + threadIdx.x;
    if (i < NSUB) subcursor[i] = i * CAP2;
}

// ---------------- Single-level bucket scatter (replaces super+sub) ----------
// Per block: LDS-histogram ranks over 1172 buckets, ONE global atomicAdd per
// (block,bucket) to claim a contiguous run, then per-edge writes at
// base+rank. Runs avg 7 edges (56B) -> near-line write granularity (the
// round-5 failure was per-edge random 8B windows; this keeps block-contiguous
// runs like the two-level version but in one pass).
// meta.x = (row&127)<<18 | col, meta.y = val f32 bits (row_sort finalizes).
// Blocks >= N_TILES do the independent ego->fp16 convert.
__global__ __launch_bounds__(512) void scatter_kernel(const int* __restrict__ rows,
                                                      const int* __restrict__ cols,
                                                      const float* __restrict__ vals,
                                                      int* __restrict__ subcursor,
                                                      int2* __restrict__ meta,
                                                      const float4* __restrict__ ue4,
                                                      const float4* __restrict__ ie4,
                                                      uint2* __restrict__ e2) {
    int tid = threadIdx.x;

    if (blockIdx.x >= N_TILES) {
        // fused convert: ego -> fp16, 4 float4 per thread
        int g0 = (blockIdx.x - N_TILES) * CONV_PER_BLK + tid;
        #pragma unroll
        for (int k = 0; k < 4; ++k) {
            int g = g0 + k * 512;
            if (g < CONV_THREADS) {
                float4 f = (g < U_CNT * 16) ? ue4[g] : ie4[g - U_CNT * 16];
                half2_t a = { (half_t)f.x, (half_t)f.y };
                half2_t b = { (half_t)f.z, (half_t)f.w };
                uint2 o; o.x = h22u(a); o.y = h22u(b);
                e2[g] = o;
            }
        }
        return;
    }

    __shared__ int lcnt[NSUB];
    __shared__ int gbase[NSUB];

    for (int i = tid; i < NSUB; i += 512) lcnt[i] = 0;
    __syncthreads();

    int base = blockIdx.x * TILE_E;
    int nk = NNZ_E - base - tid;
    nk = (nk <= 0) ? 0 : (nk + 511) >> 9;

    // load + LDS rank (avg 7 edges/bucket/block -> low contention)
    int pk[16]; float vv[16]; int sb[16]; int rk[16];
    #pragma unroll
    for (int k = 0; k < 16; ++k) {
        if (k < nk) {
            int j = base + tid + (k << 9);
            int r = rows[j];
            int c = cols[j];
            vv[k] = vals[j];
            sb[k] = r >> 7;
            pk[k] = ((r & 127) << 18) | c;
            rk[k] = atomicAdd(&lcnt[sb[k]], 1);
        }
    }
    __syncthreads();

    // one global claim per (block,bucket); subcursor is 4.7KB, L2-resident
    for (int i = tid; i < NSUB; i += 512) {
        int c = lcnt[i];
        gbase[i] = (c > 0) ? atomicAdd(&subcursor[i], c) : 0;
    }
    __syncthreads();

    // per-edge write at block-contiguous run position
    #pragma unroll
    for (int k = 0; k < 16; ++k) {
        if (k < nk) {
            int pos = gbase[sb[k]] + rk[k];
            if (pos < (sb[k] + 1) * CAP2)
                meta[pos] = make_int2(pk[k], __float_as_int(vv[k]));
        }
    }
}

// Pass 2: per 128-row bucket: count rows in LDS, block scan, write sorted
// bucket back in place. Final CSR entry: x = col, y = half2(val,val) bits.
__global__ __launch_bounds__(256) void row_sort_kernel(const int* __restrict__ subcursor,
                                                       int2* __restrict__ meta,
                                                       int* __restrict__ rstart,
                                                       int* __restrict__ rend) {
    __shared__ int2 stage[CAP2];
    __shared__ int rcnt[128];
    __shared__ int scan[128];
    __shared__ int cur[128];
    int g = blockIdx.x;
    int base = g * CAP2;
    int cnt = subcursor[g] - base;
    if (cnt > CAP2) cnt = CAP2;
    int tid = threadIdx.x;
    int r0 = g << 7;

    if (tid < 128) rcnt[tid] = 0;
    __syncthreads();

    for (int i = tid; i < cnt; i += 256) {
        int2 e = meta[base + i];
        stage[i] = e;
        atomicAdd(&rcnt[((uint)e.x >> 18) & 127], 1);
    }
    __syncthreads();

    if (tid < 128) scan[tid] = rcnt[tid];
    __syncthreads();
    for (int off = 1; off < 128; off <<= 1) {
        int t = (tid < 128 && tid >= off) ? scan[tid - off] : 0;
        __syncthreads();
        if (tid < 128) scan[tid] += t;
        __syncthreads();
    }
    if (tid < 128) {
        int excl = scan[tid] - rcnt[tid];
        cur[tid] = excl;
        int r = r0 + tid;
        if (r < N_NODES) {
            rstart[r] = base + excl;
            rend[r]   = base + scan[tid];
        }
    }
    __syncthreads();

    for (int i = tid; i < cnt; i += 256) {
        int2 e = stage[i];
        int rl = ((uint)e.x >> 18) & 127;
        int pos = atomicAdd(&cur[rl], 1);
        float v = __int_as_float(e.y);
        half2_t hv = { (half_t)v, (half_t)v };
        meta[base + pos] = make_int2(e.x & 0x3FFFF, (int)h22u(hv));
    }
}

// ---------------- SpMM (gather-only, fp16 features, pk_fma) ----------------
// Wave: 8 edge-slots x 8 lanes; lane loads 16B (8 fp16) of the 128B row.
// 4-deep edge pipeline. Phantom slots clamp to THIS ROW's last edge with
// val=0: cache hits on lines the wave needs anyway (no global hot-spot).
__global__ __launch_bounds__(256) void spmm_fp16_kernel(const int* __restrict__ rstart,
                                                        const int* __restrict__ rend,
                                                        const int2* __restrict__ csr,
                                                        const ushort_t* __restrict__ x,
                                                        ushort_t* __restrict__ out) {
    int wid  = (blockIdx.x * blockDim.x + threadIdx.x) >> 6;
    int lane = threadIdx.x & 63;
    int sub  = lane >> 3;   // edge slot 0..7
    int l8   = lane & 7;    // 16B chunk within row
    if (wid >= N_NODES) return;
    int s = rstart[wid], e = rend[wid];
    const uint4* x4 = (const uint4*)x;

    int last = e - 1; if (last < s) last = s;   // clamp target (valid memory)
    auto ld = [&](int jj) -> int2 {
        int2 c = csr[jj < e ? jj : last];
        if (jj >= e) c.y = 0;                   // phantom: exact-zero contribution
        return c;
    };

    half2_t a0 = { (half_t)0, (half_t)0 };
    half2_t a1 = a0, a2 = a0, a3 = a0;

    int j = s + sub;
    int2 c0 = ld(j);
    int2 c1 = ld(j + 8);
    int2 c2 = ld(j + 16);
    int2 c3 = ld(j + 24);
    for (; j < e; j += 32) {
        uint4 x0 = x4[(size_t)(c0.x & 0x3FFFF) * 8 + l8];
        uint4 x1 = x4[(size_t)(c1.x & 0x3FFFF) * 8 + l8];
        uint4 x2 = x4[(size_t)(c2.x & 0x3FFFF) * 8 + l8];
        uint4 x3 = x4[(size_t)(c3.x & 0x3FFFF) * 8 + l8];
        int jn = j + 32;
        int2 n0 = ld(jn);
        int2 n1 = ld(jn + 8);
        int2 n2 = ld(jn + 16);
        int2 n3 = ld(jn + 24);
        half2_t v0 = u2h2((uint)c0.y);
        a0 += u2h2(x0.x) * v0; a1 += u2h2(x0.y) * v0;
        a2 += u2h2(x0.z) * v0; a3 += u2h2(x0.w) * v0;
        half2_t v1 = u2h2((uint)c1.y);
        a0 += u2h2(x1.x) * v1; a1 += u2h2(x1.y) * v1;
        a2 += u2h2(x1.z) * v1; a3 += u2h2(x1.w) * v1;
        half2_t v2 = u2h2((uint)c2.y);
        a0 += u2h2(x2.x) * v2; a1 += u2h2(x2.y) * v2;
        a2 += u2h2(x2.z) * v2; a3 += u2h2(x2.w) * v2;
        half2_t v3 = u2h2((uint)c3.y);
        a0 += u2h2(x3.x) * v3; a1 += u2h2(x3.y) * v3;
        a2 += u2h2(x3.z) * v3; a3 += u2h2(x3.w) * v3;
        c0 = n0; c1 = n1; c2 = n2; c3 = n3;
    }
    a0 += h2shfl_xor(a0, 8);  a1 += h2shfl_xor(a1, 8);
    a2 += h2shfl_xor(a2, 8);  a3 += h2shfl_xor(a3, 8);
    a0 += h2shfl_xor(a0, 16); a1 += h2shfl_xor(a1, 16);
    a2 += h2shfl_xor(a2, 16); a3 += h2shfl_xor(a3, 16);
    a0 += h2shfl_xor(a0, 32); a1 += h2shfl_xor(a1, 32);
    a2 += h2shfl_xor(a2, 32); a3 += h2shfl_xor(a3, 32);

    if (sub == 0) {
        uint4 r;
        r.x = h22u(a0); r.y = h22u(a1); r.z = h22u(a2); r.w = h22u(a3);
        ((uint4*)out)[(size_t)wid * 8 + l8] = r;
    }
}

// ---------------- Epilogue ----------------
__global__ __launch_bounds__(256) void epilogue_kernel(const int* __restrict__ users,
                                                       const int* __restrict__ items,
                                                       const int* __restrict__ rstart,
                                                       const int* __restrict__ rend,
                                                       const int2* __restrict__ csr,
                                                       const ushort_t* __restrict__ ebuf,
                                                       const ushort_t* __restrict__ buf1,
                                                       const ushort_t* __restrict__ buf2,
                                                       const float* __restrict__ u_his,
                                                       const float* __restrict__ i_his,
                                                       const float* __restrict__ W,
                                                       const float* __restrict__ bvec,
                                                       float* __restrict__ out) {
    __shared__ float Wt[D_DIM * 65];
    __shared__ float bsh[D_DIM];
    __shared__ float on_s[4][D_DIM];
    for (int t = threadIdx.x; t < D_DIM * D_DIM; t += blockDim.x) {
        int j = t >> 6, k = t & 63;
        Wt[k * 65 + j] = W[t];
    }
    if (threadIdx.x < D_DIM) bsh[threadIdx.x] = bvec[threadIdx.x];

    int wv   = threadIdx.x >> 6;
    int wid  = blockIdx.x * 4 + wv;
    int lane = threadIdx.x & 63;
    int sub  = lane >> 4;   // 4 edge slots
    int l16  = lane & 15;   // 8B chunk (4 fp16) within 128B row

    bool is_user = (wid < B_SZ);
    int  samp = is_user ? wid : wid - B_SZ;
    int  idx  = is_user ? users[samp] : items[samp];
    int  row  = is_user ? idx : (U_CNT + idx);

    // hoist latency-long independent loads above the gather chain
    const float* his = is_user ? u_his : i_his;
    float hisv = his[(size_t)idx * D_DIM + lane];
    uint2 eg = make_uint2(0, 0), b1v = eg, b2v = eg;
    if (sub == 0) {
        eg  = ((const uint2*)ebuf)[(size_t)row * 16 + l16];
        b1v = ((const uint2*)buf1)[(size_t)row * 16 + l16];
        b2v = ((const uint2*)buf2)[(size_t)row * 16 + l16];
    }

    // layer-3 gather from buf2 (fp16, pk_fma), 4-deep edge pipeline, clamped
    int s = rstart[row], e = rend[row];
    int last = e - 1; if (last < s) last = s;
    auto ld = [&](int jj) -> int2 {
        int2 c = csr[jj < e ? jj : last];
        if (jj >= e) c.y = 0;
        return c;
    };
    half2_t c0 = { (half_t)0, (half_t)0 };
    half2_t c1 = c0;
    int j = s + sub;
    int2 e0 = ld(j);
    int2 e1 = ld(j + 4);
    int2 e2 = ld(j + 8);
    int2 e3 = ld(j + 12);
    for (; j < e; j += 16) {
        uint2 x0 = ((const uint2*)buf2)[(size_t)(e0.x & 0x3FFFF) * 16 + l16];
        uint2 x1 = ((const uint2*)buf2)[(size_t)(e1.x & 0x3FFFF) * 16 + l16];
        uint2 x2 = ((const uint2*)buf2)[(size_t)(e2.x & 0x3FFFF) * 16 + l16];
        uint2 x3 = ((const uint2*)buf2)[(size_t)(e3.x & 0x3FFFF) * 16 + l16];
        int jn = j + 16;
        int2 n0 = ld(jn);
        int2 n1 = ld(jn + 4);
        int2 n2 = ld(jn + 8);
        int2 n3 = ld(jn + 12);
        half2_t v0 = u2h2((uint)e0.y);
        c0 += u2h2(x0.x) * v0; c1 += u2h2(x0.y) * v0;
        half2_t v1 = u2h2((uint)e1.y);
        c0 += u2h2(x1.x) * v1; c1 += u2h2(x1.y) * v1;
        half2_t v2 = u2h2((uint)e2.y);
        c0 += u2h2(x2.x) * v2; c1 += u2h2(x2.y) * v2;
        half2_t v3 = u2h2((uint)e3.y);
        c0 += u2h2(x3.x) * v3; c1 += u2h2(x3.y) * v3;
        e0 = n0; e1 = n1; e2 = n2; e3 = n3;
    }
    c0 += h2shfl_xor(c0, 16); c1 += h2shfl_xor(c1, 16);
    c0 += h2shfl_xor(c0, 32); c1 += h2shfl_xor(c1, 32);

    if (sub == 0) {
        on_s[wv][l16 * 4 + 0] = (h2lo(eg.x) + h2lo(b1v.x) + h2lo(b2v.x) + (float)c0[0]) * 0.25f;
        on_s[wv][l16 * 4 + 1] = (h2hi(eg.x) + h2hi(b1v.x) + h2hi(b2v.x) + (float)c0[1]) * 0.25f;
        on_s[wv][l16 * 4 + 2] = (h2lo(eg.y) + h2lo(b1v.y) + h2lo(b2v.y) + (float)c1[0]) * 0.25f;
        on_s[wv][l16 * 4 + 3] = (h2hi(eg.y) + h2hi(b1v.y) + h2hi(b2v.y) + (float)c1[1]) * 0.25f;
    }
    __syncthreads();

    float online = on_s[wv][lane];
    float target = 0.05f * hisv + 0.95f * online;

    float p = bsh[lane];
    #pragma unroll
    for (int k = 0; k < D_DIM; ++k) {
        float ok = __shfl(online, k, 64);
        p = fmaf(ok, Wt[k * 65 + lane], p);
    }

    size_t base = is_user ? 0 : (size_t)2 * B_SZ * D_DIM;
    out[base + (size_t)samp * D_DIM + lane] = p;
    out[base + (size_t)B_SZ * D_DIM + (size_t)samp * D_DIM + lane] = target;
}

// ---------------- launch ----------------

extern "C" void kernel_launch(void* const* d_in, const int* in_sizes, int n_in,
                              void* d_out, int out_size, void* d_ws, size_t ws_size,
                              hipStream_t stream) {
    const float* user_emb = (const float*)d_in[0];
    const float* item_emb = (const float*)d_in[1];
    const float* W        = (const float*)d_in[2];
    const float* bvec     = (const float*)d_in[3];
    const int*   adj_rows = (const int*)d_in[4];
    const int*   adj_cols = (const int*)d_in[5];
    const float* adj_vals = (const float*)d_in[6];
    const int*   users    = (const int*)d_in[7];
    const int*   items    = (const int*)d_in[8];
    const float* u_his    = (const float*)d_in[9];
    const float* i_his    = (const float*)d_in[10];
    float* out = (float*)d_out;

    char* ws = (char*)d_ws;
    size_t o = 0;
    ushort_t* ebuf  = (ushort_t*)(ws + o); o += (size_t)N_NODES * D_DIM * 2;     // 19.2MB
    ushort_t* buf1  = (ushort_t*)(ws + o); o += (size_t)N_NODES * D_DIM * 2;     // 19.2MB
    ushort_t* buf2  = (ushort_t*)(ws + o); o += (size_t)N_NODES * D_DIM * 2;     // 19.2MB
    int2*  meta     = (int2*)(ws + o);     o += (size_t)NSUB * CAP2 * 8;         // 38.4MB
    int*   rstart   = (int*)(ws + o);      o += (size_t)N_NODES * 4;
    int*   rend     = (int*)(ws + o);      o += (size_t)N_NODES * 4;
    int*   subcursor= (int*)(ws + o);      o += (size_t)NSUB * 4;
    (void)ws_size; (void)o; (void)in_sizes; (void)n_in; (void)out_size;

    // single-level bucket scatter (replaces super+sub); conv rides along
    init_cursors_kernel<<<(NSUB + 255) / 256, 256, 0, stream>>>(subcursor);
    scatter_kernel<<<N_TILES + CONV_BLOCKS, 512, 0, stream>>>(
        adj_rows, adj_cols, adj_vals, subcursor, meta,
        (const float4*)user_emb, (const float4*)item_emb, (uint2*)ebuf);
    row_sort_kernel<<<NSUB, 256, 0, stream>>>(subcursor, meta, rstart, rend);

    // layers 1 and 2 (full, fp16); layer 3 fused into epilogue
    int spmm_blocks = (N_NODES + 3) / 4;
    spmm_fp16_kernel<<<spmm_blocks, 256, 0, stream>>>(rstart, rend, meta, ebuf, buf1);
    spmm_fp16_kernel<<<spmm_blocks, 256, 0, stream>>>(rstart, rend, meta, buf1, buf2);

    epilogue_kernel<<<(2 * B_SZ) / 4, 256, 0, stream>>>(users, items, rstart, rend, meta,
                                                        ebuf, buf1, buf2,
                                                        u_his, i_his, W, bvec, out);
}